// Round 7
// baseline (513.441 us; speedup 1.0000x reference)
//
#include <hip/hip_runtime.h>
#include <hip/hip_bf16.h>

// ---------- types ----------
typedef __attribute__((ext_vector_type(8))) short short8;
typedef __attribute__((ext_vector_type(4))) float f32x4;

static __device__ __forceinline__ unsigned short f2bf(float x) {
  union { __hip_bfloat16 h; unsigned short u; } cv;
  cv.h = __float2bfloat16(x);
  return cv.u;
}

// XCD-chunked swizzle (T1): contiguous logical-tile ranges per XCD (nwg%8==0).
// Verified r3->r4: FETCH 545MB -> 65MB on the scores/SPW GEMMs.
static __device__ __forceinline__ void xcd_swizzle(unsigned& bx, unsigned& by, unsigned& bz) {
  unsigned nwg = gridDim.x * gridDim.y * gridDim.z;
  unsigned lin = blockIdx.x + gridDim.x * (blockIdx.y + gridDim.y * blockIdx.z);
  unsigned chunk = nwg >> 3;
  lin = (lin & 7) * chunk + (lin >> 3);
  bx = lin % gridDim.x;
  unsigned tmp = lin / gridDim.x;
  by = tmp % gridDim.y;
  bz = tmp / gridDim.y;
}

// ---------- cast fp32 -> bf16 over up to 10 concatenated segments ----------
struct CastDesc { const float* s[10]; long cum[11]; };

__global__ void castN_kernel(CastDesc d, unsigned short* __restrict__ dst, long N4) {
  for (long i = blockIdx.x * (long)blockDim.x + threadIdx.x; i < N4;
       i += (long)gridDim.x * blockDim.x) {
    long e = i << 2;
    int seg = 0;
#pragma unroll
    for (int j = 1; j < 10; ++j) seg += (e >= d.cum[j]) ? 1 : 0;
    const float* s = d.s[seg];
    long off = e - d.cum[seg];
    float4 v = *reinterpret_cast<const float4*>(s + off);
    ushort4 o;
    o.x = f2bf(v.x); o.y = f2bf(v.y); o.z = f2bf(v.z); o.w = f2bf(v.w);
    *reinterpret_cast<ushort4*>(dst + e) = o;
  }
}

// ---------- transpose-cast: fp32 [R,C] -> bf16 [C,R], batched over z ----------
__global__ __launch_bounds__(256)
void tcast_kernel(const float* __restrict__ in, unsigned short* __restrict__ out,
                  int R, int C, long sIn, long sOut) {
  __shared__ float tile[64][65];
  int z = blockIdx.z;
  const float* src = in + (long)z * sIn;
  unsigned short* dst = out + (long)z * sOut;
  int r0 = blockIdx.y * 64, c0 = blockIdx.x * 64;
  int t = threadIdx.x;
  int lr = t >> 4;          // 0..15
  int lc = (t & 15) * 4;    // 0,4,..,60
#pragma unroll
  for (int j = 0; j < 4; ++j) {
    int r = lr + j * 16;
    float4 v = *reinterpret_cast<const float4*>(src + (long)(r0 + r) * C + c0 + lc);
    tile[r][lc] = v.x; tile[r][lc + 1] = v.y; tile[r][lc + 2] = v.z; tile[r][lc + 3] = v.w;
  }
  __syncthreads();
#pragma unroll
  for (int j = 0; j < 4; ++j) {
    int oc = lr + j * 16;
    ushort4 o;
    o.x = f2bf(tile[lc][oc]);
    o.y = f2bf(tile[lc + 1][oc]);
    o.z = f2bf(tile[lc + 2][oc]);
    o.w = f2bf(tile[lc + 3][oc]);
    *reinterpret_cast<ushort4*>(dst + (long)(c0 + oc) * R + r0 + lc) = o;
  }
}

// ---------- fused 4-branch transpose-cast: emb_i [1024,C_i] -> concat^T [960,1024] ----------
// x-tile -> branch: {0}=br0, {1,2}=br1, {3..6}=br2, {7..14}=br3 (1+2+4+8 = 15 tiles of 64 cols).
struct T4Desc { const float* src[4]; };

__global__ __launch_bounds__(256)
void tcast4_kernel(T4Desc d, unsigned short* __restrict__ out) {
  __shared__ float tile[64][65];
  const int Cb_[4] = {64, 128, 256, 512};
  const int xo_[4] = {0, 1, 3, 7};
  const int g0_[4] = {0, 64, 192, 448};
  int x = blockIdx.x;
  int br = (x >= 7) ? 3 : (x >= 3) ? 2 : (x >= 1) ? 1 : 0;
  int C = Cb_[br];
  int c0loc = (x - xo_[br]) * 64;
  int c0glob = g0_[br] + c0loc;
  int z = blockIdx.z;
  const float* src = d.src[br] + (long)z * 1024 * C;
  unsigned short* dst = out + (long)z * 983040;
  int r0 = blockIdx.y * 64;
  int t = threadIdx.x;
  int lr = t >> 4;
  int lc = (t & 15) * 4;
#pragma unroll
  for (int j = 0; j < 4; ++j) {
    int r = lr + j * 16;
    float4 v = *reinterpret_cast<const float4*>(src + (long)(r0 + r) * C + c0loc + lc);
    tile[r][lc] = v.x; tile[r][lc + 1] = v.y; tile[r][lc + 2] = v.z; tile[r][lc + 3] = v.w;
  }
  __syncthreads();
#pragma unroll
  for (int j = 0; j < 4; ++j) {
    int oc = lr + j * 16;
    ushort4 o;
    o.x = f2bf(tile[lc][oc]);
    o.y = f2bf(tile[lc + 1][oc]);
    o.z = f2bf(tile[lc + 2][oc]);
    o.w = f2bf(tile[lc + 3][oc]);
    *reinterpret_cast<ushort4*>(dst + (long)(c0glob + oc) * 1024 + r0 + lc) = o;
  }
}

// ---------- y-tile descriptor for branch-aligned tiling ----------
struct YDesc { int m0[8]; int mw[8]; int br[8]; };

// ---------- generic NT bf16 MFMA GEMM, TM x TN tile, 256 threads ----------
// 2-phase double-buffered staging (r5-proven best: scores 103.9us, occ 27%):
// issue next K-step's global_load_lds BEFORE computing current; single
// __syncthreads per step (drains vmcnt+lgkmcnt -> race-free). nInner folds a
// reduction (e.g. heads) by walking A/B base pointers by iA/iB every K cols.
// [r6 post-mortem: depth-2 counted-vmcnt + 4 buffers REGRESSED (66KB LDS ->
//  occupancy 27->20.6%, scores 104->111us). Wave-level overlap from
//  co-resident blocks beats intra-block pipelining here — m131/m132.]
template<int TM, int TN, int OUT, int DO_STATS, int YD>
__global__ __launch_bounds__(256)
void gemm_nt(const unsigned short* __restrict__ A,
             const unsigned short* __restrict__ B,
             void* __restrict__ Cp,
             int K, int lda, int ldb, long ldc, int Hdiv,
             long sAb, long sAh, long sBb, long sBh, long sC,
             int nInner, long iA, long iB,
             float alpha, float* __restrict__ stats,
             int Mclamp, int Nclamp, int Mwrite, int Nwrite, int Nvalid, YDesc yd) {
  constexpr int WM = TM / 32, WN = TN / 32;
  __shared__ unsigned short As[2][TM * 32];
  __shared__ unsigned short Bs[2][TN * 32];
  __shared__ float red[8];

  unsigned bxu, byu, bzu;
  xcd_swizzle(bxu, byu, bzu);
  int z = (int)bzu;
  int b = z / Hdiv, h = z % Hdiv;
  const unsigned short* Ab = A + (long)b * sAb + (long)h * sAh;
  const unsigned short* Bb = B + (long)b * sBb + (long)h * sBh;
  int y = (int)byu;
  int m0 = YD ? yd.m0[y] : y * TM;
  int rowLimit = YD ? (m0 + yd.mw[y]) : Mwrite;
  int n0 = (int)bxu * TN;
  int t = threadIdx.x;
  int lane = t & 63, wave = t >> 6;
  int wm = (wave >> 1) * (TM / 2), wn = (wave & 1) * (TN / 2);
  int l15 = lane & 15, q = lane >> 4;
  int arow = t >> 2, acol = (t & 3) * 8;

  int rA[TM / 64], rB[TN / 64];
#pragma unroll
  for (int r = 0; r < TM / 64; ++r) rA[r] = min(m0 + r * 64 + arow, Mclamp - 1);
#pragma unroll
  for (int r = 0; r < TN / 64; ++r) rB[r] = min(n0 + r * 64 + arow, Nclamp - 1);

  int kSteps = K >> 5;
  int nt = nInner * kSteps;
  const unsigned short* Asrc = Ab;
  const unsigned short* Bsrc = Bb;
  int kk = 0;

  auto stage = [&](int bufSel) {
#pragma unroll
    for (int r = 0; r < TM / 64; ++r)
      __builtin_amdgcn_global_load_lds(
          (const __attribute__((address_space(1))) void*)(Asrc + (long)rA[r] * lda + acol + kk),
          (__attribute__((address_space(3))) void*)(&As[bufSel][r * 2048 + t * 8]), 16, 0, 0);
#pragma unroll
    for (int r = 0; r < TN / 64; ++r)
      __builtin_amdgcn_global_load_lds(
          (const __attribute__((address_space(1))) void*)(Bsrc + (long)rB[r] * ldb + acol + kk),
          (__attribute__((address_space(3))) void*)(&Bs[bufSel][r * 2048 + t * 8]), 16, 0, 0);
  };
  auto advance = [&]() { kk += 32; if (kk >= K) { kk = 0; Asrc += iA; Bsrc += iB; } };

  f32x4 acc[WM][WN] = {};
  stage(0);
  advance();
  __syncthreads();
  for (int s = 0; s < nt; ++s) {
    int cur = s & 1;
    if (s + 1 < nt) { stage(cur ^ 1); advance(); }
    short8 af[WM], bfr[WN];
#pragma unroll
    for (int i = 0; i < WM; ++i)
      af[i] = *reinterpret_cast<const short8*>(&As[cur][(wm + i * 16 + l15) * 32 + q * 8]);
#pragma unroll
    for (int j = 0; j < WN; ++j)
      bfr[j] = *reinterpret_cast<const short8*>(&Bs[cur][(wn + j * 16 + l15) * 32 + q * 8]);
#pragma unroll
    for (int i = 0; i < WM; ++i)
#pragma unroll
      for (int j = 0; j < WN; ++j)
        acc[i][j] = __builtin_amdgcn_mfma_f32_16x16x32_bf16(af[i], bfr[j], acc[i][j], 0, 0, 0);
    __syncthreads();
  }

  long cbase = (long)z * sC;
  float ssum = 0.f, ssq = 0.f;
#pragma unroll
  for (int i = 0; i < WM; ++i)
#pragma unroll
    for (int j = 0; j < WN; ++j)
#pragma unroll
      for (int r = 0; r < 4; ++r) {
        float v = acc[i][j][r] * alpha;
        int rg = m0 + wm + i * 16 + q * 4 + r;
        int cg = n0 + wn + j * 16 + l15;
        if (rg < rowLimit && cg < Nwrite) {
          long idx = cbase + (long)rg * ldc + cg;
          if (OUT == 1) ((float*)Cp)[idx] = v;
          else if (OUT == 2) ((_Float16*)Cp)[idx] = (_Float16)v;
          else ((unsigned short*)Cp)[idx] = f2bf(v);
        }
        if (DO_STATS && rg < rowLimit && cg < Nvalid) { ssum += v; ssq += v * v; }
      }

  if (DO_STATS) {
#pragma unroll
    for (int o = 32; o; o >>= 1) {
      ssum += __shfl_down(ssum, o, 64);
      ssq  += __shfl_down(ssq,  o, 64);
    }
    if (lane == 0) { red[wave] = ssum; red[wave + 4] = ssq; }
    __syncthreads();
    if (t == 0) {
      long slot = YD ? ((long)z * 8 + yd.br[y] * 2) : ((long)z * 2);
      atomicAdd(stats + slot,     red[0] + red[1] + red[2] + red[3]);
      atomicAdd(stats + slot + 1, red[4] + red[5] + red[6] + red[7]);
    }
  }
}

// ---------- block-diagonal A GEMM: T[b,h] = Wq_br[h] @ G[b] (per y-tile branch) ----------
struct BDesc { int K[8]; int aRow0[8]; int out0[8]; int mw[8]; int bc[8]; long aOff[8]; long aH[8]; };

__global__ __launch_bounds__(256)
void gemm_bd(const unsigned short* __restrict__ A0,
             const unsigned short* __restrict__ B0,
             unsigned short* __restrict__ Cp,
             int ldb, long sBz, long sC, BDesc d) {
  constexpr int TM = 128, TN = 64, WM = 4, WN = 2;
  __shared__ unsigned short As[2][TM * 32];
  __shared__ unsigned short Bs[2][TN * 32];
  unsigned bxu, byu, bzu;
  xcd_swizzle(bxu, byu, bzu);
  int z = (int)bzu;
  int b = z >> 2, h = z & 3;
  int y = (int)byu;
  int K = d.K[y];
  const unsigned short* Ab = A0 + d.aOff[y] + (long)h * d.aH[y];
  const unsigned short* Bb = B0 + (long)b * sBz + d.bc[y];
  int n0 = (int)bxu * TN;
  int t = threadIdx.x;
  int lane = t & 63, wave = t >> 6;
  int wm = (wave >> 1) * 64, wn = (wave & 1) * 32;
  int l15 = lane & 15, q = lane >> 4;
  int arow = t >> 2, acol = (t & 3) * 8;

  int rA0 = min(d.aRow0[y] + arow, K - 1);
  int rA1 = min(d.aRow0[y] + 64 + arow, K - 1);
  int rB0 = n0 + arow;

  int kk = 0;
  auto stage = [&](int bufSel) {
    __builtin_amdgcn_global_load_lds(
        (const __attribute__((address_space(1))) void*)(Ab + (long)rA0 * K + acol + kk),
        (__attribute__((address_space(3))) void*)(&As[bufSel][t * 8]), 16, 0, 0);
    __builtin_amdgcn_global_load_lds(
        (const __attribute__((address_space(1))) void*)(Ab + (long)rA1 * K + acol + kk),
        (__attribute__((address_space(3))) void*)(&As[bufSel][2048 + t * 8]), 16, 0, 0);
    __builtin_amdgcn_global_load_lds(
        (const __attribute__((address_space(1))) void*)(Bb + (long)rB0 * ldb + acol + kk),
        (__attribute__((address_space(3))) void*)(&Bs[bufSel][t * 8]), 16, 0, 0);
  };

  int nt = K >> 5;
  f32x4 acc[WM][WN] = {};
  stage(0);
  kk += 32;
  __syncthreads();
  for (int s = 0; s < nt; ++s) {
    int cur = s & 1;
    if (s + 1 < nt) { stage(cur ^ 1); kk += 32; }
    short8 af[WM], bfr[WN];
#pragma unroll
    for (int i = 0; i < WM; ++i)
      af[i] = *reinterpret_cast<const short8*>(&As[cur][(wm + i * 16 + l15) * 32 + q * 8]);
#pragma unroll
    for (int j = 0; j < WN; ++j)
      bfr[j] = *reinterpret_cast<const short8*>(&Bs[cur][(wn + j * 16 + l15) * 32 + q * 8]);
#pragma unroll
    for (int i = 0; i < WM; ++i)
#pragma unroll
      for (int j = 0; j < WN; ++j)
        acc[i][j] = __builtin_amdgcn_mfma_f32_16x16x32_bf16(af[i], bfr[j], acc[i][j], 0, 0, 0);
    __syncthreads();
  }

  long cbase = (long)z * sC;
  int mw = d.mw[y], out0 = d.out0[y];
#pragma unroll
  for (int i = 0; i < WM; ++i)
#pragma unroll
    for (int j = 0; j < WN; ++j)
#pragma unroll
      for (int r = 0; r < 4; ++r) {
        int loc = wm + i * 16 + q * 4 + r;
        int cg = n0 + wn + j * 16 + l15;
        if (loc < mw) {
          long idx = cbase + (long)(out0 + loc) * 960 + cg;
          Cp[idx] = f2bf(acc[i][j][r]);
        }
      }
}

// ---------- instance-norm + softmax over KV=960, in-place fp16 -> bf16 ----------
__global__ __launch_bounds__(256)
void norm_softmax_all(_Float16* __restrict__ S, const float* __restrict__ stats) {
  long row = blockIdx.x;            // z*960 + cc
  int z = (int)(row / 960), cc = (int)(row % 960);
  int br = (cc < 64) ? 0 : (cc < 192) ? 1 : (cc < 448) ? 2 : 3;
  int Cbr = (br == 0) ? 64 : (br == 1) ? 128 : (br == 2) ? 256 : 512;
  float invCnt = 1.0f / ((float)Cbr * 960.0f);
  float m1 = stats[z * 8 + br * 2 + 0] * invCnt;
  float m2 = stats[z * 8 + br * 2 + 1] * invCnt;
  float rsig = rsqrtf(m2 - m1 * m1 + 1e-5f);
  _Float16* s = S + row * 960;
  int t = threadIdx.x;
  float e[4]; float acc = 0.f;
#pragma unroll
  for (int j = 0; j < 4; ++j) {
    int i = t + j * 256;
    if (i < 960) { e[j] = __expf(((float)s[i] - m1) * rsig); acc += e[j]; }
    else e[j] = 0.f;
  }
#pragma unroll
  for (int o = 32; o; o >>= 1) acc += __shfl_down(acc, o, 64);
  __shared__ float red[4];
  if ((t & 63) == 0) red[t >> 6] = acc;
  __syncthreads();
  float inv = 1.0f / (red[0] + red[1] + red[2] + red[3]);
  unsigned short* p = (unsigned short*)s;
#pragma unroll
  for (int j = 0; j < 4; ++j) {
    int i = t + j * 256;
    if (i < 960) p[i] = f2bf(e[j] * inv);
  }
}

// ---------- 4-branch batched NT GEMM (out-proj), branch from bx ----------
struct MDesc {
  long aOff[4], bOff[4], cOff[4];
  long sAz[4], sBz[4], sCz[4];
  long iA[4], iB[4];
  int  lda[4], ldb[4], ldcv[4];
  int  Kk[4], Ncl[4], nIn[4];
  int  nstart[4];
  float alpha[4];
};

template<int OUT_F32>
__global__ __launch_bounds__(256)
void gemm_multi(const unsigned short* __restrict__ A0,
                const unsigned short* __restrict__ B0,
                void* __restrict__ Cp, MDesc d) {
  __shared__ unsigned short As[2][128 * 32];
  __shared__ unsigned short Bs[2][128 * 32];
  unsigned bxu, byu, bzu;
  xcd_swizzle(bxu, byu, bzu);
  int bx = (int)bxu;
  int br = (bx >= d.nstart[3]) ? 3 : (bx >= d.nstart[2]) ? 2 : (bx >= d.nstart[1]) ? 1 : 0;
  int z = (int)bzu;
  int n0 = (bx - d.nstart[br]) * 128;
  int m0 = (int)byu * 128;
  int K = d.Kk[br], lda = d.lda[br], ldb = d.ldb[br], ldc = d.ldcv[br];
  int Ncl = d.Ncl[br], nInner = d.nIn[br];
  long iA = d.iA[br], iB = d.iB[br];
  float alpha = d.alpha[br];
  const unsigned short* Ab = A0 + d.aOff[br] + (long)z * d.sAz[br];
  const unsigned short* Bb = B0 + d.bOff[br] + (long)z * d.sBz[br];

  int t = threadIdx.x, lane = t & 63, wave = t >> 6;
  int wm = (wave >> 1) * 64, wn = (wave & 1) * 64;
  int l15 = lane & 15, q = lane >> 4;
  int arow = t >> 2, acol = (t & 3) * 8;
  int rA0 = m0 + arow, rA1 = m0 + 64 + arow;
  int rB0 = min(n0 + arow, Ncl - 1), rB1 = min(n0 + 64 + arow, Ncl - 1);

  const unsigned short* Asrc = Ab;
  const unsigned short* Bsrc = Bb;
  int kk = 0;
  auto stage = [&](int bufSel) {
    __builtin_amdgcn_global_load_lds(
        (const __attribute__((address_space(1))) void*)(Asrc + (long)rA0 * lda + acol + kk),
        (__attribute__((address_space(3))) void*)(&As[bufSel][t * 8]), 16, 0, 0);
    __builtin_amdgcn_global_load_lds(
        (const __attribute__((address_space(1))) void*)(Asrc + (long)rA1 * lda + acol + kk),
        (__attribute__((address_space(3))) void*)(&As[bufSel][2048 + t * 8]), 16, 0, 0);
    __builtin_amdgcn_global_load_lds(
        (const __attribute__((address_space(1))) void*)(Bsrc + (long)rB0 * ldb + acol + kk),
        (__attribute__((address_space(3))) void*)(&Bs[bufSel][t * 8]), 16, 0, 0);
    __builtin_amdgcn_global_load_lds(
        (const __attribute__((address_space(1))) void*)(Bsrc + (long)rB1 * ldb + acol + kk),
        (__attribute__((address_space(3))) void*)(&Bs[bufSel][2048 + t * 8]), 16, 0, 0);
  };
  auto advance = [&]() { kk += 32; if (kk >= K) { kk = 0; Asrc += iA; Bsrc += iB; } };

  int nt = nInner * (K >> 5);
  f32x4 acc[4][4] = {};
  stage(0);
  advance();
  __syncthreads();
  for (int s = 0; s < nt; ++s) {
    int cur = s & 1;
    if (s + 1 < nt) { stage(cur ^ 1); advance(); }
    short8 af[4], bfr[4];
#pragma unroll
    for (int i = 0; i < 4; ++i)
      af[i] = *reinterpret_cast<const short8*>(&As[cur][(wm + i * 16 + l15) * 32 + q * 8]);
#pragma unroll
    for (int j = 0; j < 4; ++j)
      bfr[j] = *reinterpret_cast<const short8*>(&Bs[cur][(wn + j * 16 + l15) * 32 + q * 8]);
#pragma unroll
    for (int i = 0; i < 4; ++i)
#pragma unroll
      for (int j = 0; j < 4; ++j)
        acc[i][j] = __builtin_amdgcn_mfma_f32_16x16x32_bf16(af[i], bfr[j], acc[i][j], 0, 0, 0);
    __syncthreads();
  }

  long cb = d.cOff[br] + (long)z * d.sCz[br];
#pragma unroll
  for (int i = 0; i < 4; ++i)
#pragma unroll
    for (int j = 0; j < 4; ++j)
#pragma unroll
      for (int r = 0; r < 4; ++r) {
        float v = acc[i][j][r] * alpha;
        int rg = m0 + wm + i * 16 + q * 4 + r;
        int cg = n0 + wn + j * 16 + l15;
        if (cg < Ncl) {
          long idx = cb + (long)rg * ldc + cg;
          if (OUT_F32) ((float*)Cp)[idx] = v;
          else ((unsigned short*)Cp)[idx] = f2bf(v);
        }
      }
}

// ---------- host ----------
extern "C" void kernel_launch(void* const* d_in, const int* in_sizes, int n_in,
                              void* d_out, int out_size, void* d_ws, size_t ws_size,
                              hipStream_t stream) {
  const float* embs[4] = {(const float*)d_in[0], (const float*)d_in[1],
                          (const float*)d_in[2], (const float*)d_in[3]};
  const float* embA = (const float*)d_in[4];
  const float* Wk   = (const float*)d_in[9];
  const float* Wv   = (const float*)d_in[10];
  float* out = (float*)d_out;

  char* base = (char*)d_ws;
  size_t off = 0;
  auto take = [&](size_t bytes) -> void* {
    void* p = base + off;
    off += (bytes + 255) & ~(size_t)255;
    return p;
  };
  // contiguous cast destination region: EA | WQb | WKb | WOb (all 256B-multiples)
  unsigned short* EA    = (unsigned short*)take(15728640);  // embA bf16 [8][1024][960]
  unsigned short* WQb   = (unsigned short*)take(2785280);   // Wq1..4 bf16
  unsigned short* WKb   = (unsigned short*)take(7372800);   // Wk bf16 [4][960][960]
  unsigned short* WOb   = (unsigned short*)take(696320);    // Wo1..4 bf16
  unsigned short* embAT = (unsigned short*)take(15728640);  // embA^T [8][960][1024]; CT aliases
  unsigned short* embTc = (unsigned short*)take(15728640);  // concat emb^T [8][960][1024]
  unsigned short* WvT   = (unsigned short*)take(7372800);   // Wv^T [4][960][960]
  float*          ST    = (float*)take(1024);               // stats [32][4][2] f32
  unsigned short* GT    = (unsigned short*)take(14745600);  // G [8][960][960]; SPW aliases
  unsigned short* Tbuf  = (unsigned short*)take(58982400);  // T [32][960][960]
  char*           SCr   = (char*)take(58982400);            // scores fp16 -> probs bf16 in place
  _Float16*       SC    = (_Float16*)SCr;
  unsigned short* PR    = (unsigned short*)SCr;             // probs bf16 [32][960][960]
  unsigned short* SPW   = GT;                               // [8][960][960]  (G dead after T)
  unsigned short* CT    = embAT;                            // [8][1024][960] (embAT dead after G)

  if (ws_size < off) return;  // fail clean instead of faulting

  hipMemsetAsync(ST, 0, 1024, stream);

  const long Cs[4]     = {64, 128, 256, 512};
  const long c0s[4]    = {0, 64, 192, 448};
  const long woOff[4]  = {0, 4096, 20480, 86016};
  const long outOff[4] = {0, 524288, 1572864, 3670016};
  const float kscale = 0.0322748612f;  // 1/sqrt(960)
  YDesc ydDummy = {};

  // one fused cast for all plain fp32->bf16 segments (dst = EA..WOb contiguous)
  {
    CastDesc cd;
    const float* ss[10] = {embA, (const float*)d_in[5], (const float*)d_in[6],
                           (const float*)d_in[7], (const float*)d_in[8], Wk,
                           (const float*)d_in[11], (const float*)d_in[12],
                           (const float*)d_in[13], (const float*)d_in[14]};
    const long ln[10] = {7864320, 16384, 65536, 262144, 1048576, 3686400,
                         4096, 16384, 65536, 262144};
    long c = 0;
    for (int i = 0; i < 10; ++i) { cd.s[i] = ss[i]; cd.cum[i] = c; c += ln[i]; }
    cd.cum[10] = c;
    castN_kernel<<<4096, 256, 0, stream>>>(cd, EA, c >> 2);
  }
  // transpose-casts (3 launches)
  tcast_kernel<<<dim3(15, 16, 8), 256, 0, stream>>>(embA, embAT, 1024, 960, 983040, 983040);
  {
    T4Desc td; for (int i = 0; i < 4; ++i) td.src[i] = embs[i];
    tcast4_kernel<<<dim3(15, 16, 8), 256, 0, stream>>>(td, embTc);
  }
  tcast_kernel<<<dim3(15, 15, 4), 256, 0, stream>>>(Wv, WvT, 960, 960, 921600, 921600);

  // G[b][k][c] = sum_n embA[n,k]*emb_cat[n,c] : M=960, N=960, K=1024, z=8 (512 blocks)
  gemm_nt<128, 128, 0, 0, 0><<<dim3(8, 8, 8), 256, 0, stream>>>(
      embAT, embTc, GT, 1024, 1024, 1024, 960, 1,
      983040L, 0L, 983040L, 0L, 921600L,
      1, 0L, 0L, 1.0f, nullptr, 960, 960, 960, 960, 0, ydDummy);

  // T[b,h][cc][k] = Wq_br[h] @ G[b] (block-diagonal over branch rows), one launch
  {
    BDesc d;
    const int brOf[8]  = {0, 1, 2, 2, 3, 3, 3, 3};
    const int ar0[8]   = {0, 0, 0, 128, 0, 128, 256, 384};
    const long wqOff[4] = {0, 16384, 81920, 344064};
    for (int y = 0; y < 8; ++y) {
      int br = brOf[y];
      int Ci = (int)Cs[br];
      d.K[y] = Ci;
      d.aRow0[y] = ar0[y];
      d.out0[y] = (int)c0s[br] + ar0[y];
      d.mw[y] = (br == 0) ? 64 : 128;
      d.bc[y] = (int)c0s[br];
      d.aOff[y] = wqOff[br];
      d.aH[y] = (long)Ci * Ci;
    }
    gemm_bd<<<dim3(15, 8, 32), 256, 0, stream>>>(WQb, GT, Tbuf, 960, 921600L, 921600L, d);
  }

  // scores[b,h][cc][o] = kscale * T[b,h] @ Wk[h]^T, fp16 out + per-branch stats (2048 blocks)
  {
    YDesc yd;
    const int m0s[8] = {0, 64, 192, 320, 448, 576, 704, 832};
    const int mws[8] = {64, 128, 128, 128, 128, 128, 128, 128};
    const int brs[8] = {0, 1, 2, 2, 3, 3, 3, 3};
    for (int y = 0; y < 8; ++y) { yd.m0[y] = m0s[y]; yd.mw[y] = mws[y]; yd.br[y] = brs[y]; }
    gemm_nt<128, 128, 2, 1, 1><<<dim3(8, 8, 32), 256, 0, stream>>>(
        Tbuf, WKb, SC, 960, 960, 960, 960, 4,
        3686400L, 921600L, 0L, 921600L, 921600L,
        1, 0L, 0L, kscale, ST, 960, 960, 960, 960, 960, yd);
  }

  // instance-norm + softmax, in place (fp16 scores -> bf16 probs), one launch
  norm_softmax_all<<<dim3(32 * 960), 256, 0, stream>>>(SC, ST);

  // SPW[b][cc][k] = 0.25 * sum_h probs[b,h] @ WvT[h] : z=8, nInner=4 (512 blocks)
  gemm_nt<128, 128, 0, 0, 0><<<dim3(8, 8, 8), 256, 0, stream>>>(
      PR, WvT, SPW, 960, 960, 960, 960, 1,
      3686400L, 0L, 0L, 0L, 921600L,
      4, 921600L, 921600L, 0.25f, nullptr, 960, 960, 960, 960, 0, ydDummy);

  // CT[b][n][cc] = embA[b] @ SPW[b]^T : M=1024, N=960, K=960, z=8 (512 blocks)
  gemm_nt<128, 128, 0, 0, 0><<<dim3(8, 8, 8), 256, 0, stream>>>(
      EA, SPW, CT, 960, 960, 960, 960, 1,
      983040L, 0L, 921600L, 0L, 983040L,
      1, 0L, 0L, 1.0f, nullptr, 1024, 960, 1024, 960, 0, ydDummy);

  // out-all: out[b,n,c'] = CT[b][:, branch cols] @ Wo^T, one launch (512 blocks)
  {
    MDesc d;
    for (int i = 0; i < 4; ++i) {
      long C = Cs[i];
      d.aOff[i] = c0s[i];       d.sAz[i] = 983040L;          d.iA[i] = 0;
      d.bOff[i] = woOff[i];     d.sBz[i] = 0;                d.iB[i] = 0;
      d.cOff[i] = outOff[i];    d.sCz[i] = 1024L * C;
      d.lda[i] = 960; d.ldb[i] = (int)C; d.ldcv[i] = (int)C;
      d.Kk[i] = (int)C; d.Ncl[i] = (int)C; d.nIn[i] = 1;
      d.alpha[i] = 1.0f;
    }
    d.nstart[0] = 0; d.nstart[1] = 1; d.nstart[2] = 2; d.nstart[3] = 4;
    gemm_multi<1><<<dim3(8, 8, 8), 256, 0, stream>>>(CT, WOb, out, d);
  }
  (void)in_sizes; (void)n_in; (void)out_size;
}

// Round 8
// 503.260 us; speedup vs baseline: 1.0202x; 1.0202x over previous
//
#include <hip/hip_runtime.h>
#include <hip/hip_bf16.h>

// ---------- types ----------
typedef __attribute__((ext_vector_type(8))) short short8;
typedef __attribute__((ext_vector_type(4))) float f32x4;

static __device__ __forceinline__ unsigned short f2bf(float x) {
  union { __hip_bfloat16 h; unsigned short u; } cv;
  cv.h = __float2bfloat16(x);
  return cv.u;
}

// XCD-chunked swizzle (T1): contiguous logical-tile ranges per XCD (nwg%8==0).
// Verified r3->r4: FETCH 545MB -> 65MB on the scores/SPW GEMMs.
static __device__ __forceinline__ void xcd_swizzle(unsigned& bx, unsigned& by, unsigned& bz) {
  unsigned nwg = gridDim.x * gridDim.y * gridDim.z;
  unsigned lin = blockIdx.x + gridDim.x * (blockIdx.y + gridDim.y * blockIdx.z);
  unsigned chunk = nwg >> 3;
  lin = (lin & 7) * chunk + (lin >> 3);
  bx = lin % gridDim.x;
  unsigned tmp = lin / gridDim.x;
  by = tmp % gridDim.y;
  bz = tmp / gridDim.y;
}

// LDS bank swizzle (T2, BK=32, both-sides per rule #21):
//  - layout: row-major [rows][32] bf16 = 64B rows; 16B slot index s in [0,4)
//  - cell (row, s) holds global col-chunk s ^ f(row), f(row) = (row>>1)&3
//  - WRITE side: global_load_lds dest is linear (t*16B => row=t>>2, s=t&3),
//    so the SOURCE col is pre-swizzled: acol = ((t&3) ^ ((t>>3)&3)) * 8
//  - READ side: lane wants (row, chunk q): reads slot q ^ f(row)
//  Evidence r7: SQ_LDS_BANK_CONFLICT == 4.0 * ds_read_b128 count exactly.
static __device__ __forceinline__ int swz_slot(int row, int q) {
  return q ^ ((row >> 1) & 3);
}

// ---------- cast fp32 -> bf16 over up to 10 concatenated segments ----------
struct CastDesc { const float* s[10]; long cum[11]; };

__global__ void castN_kernel(CastDesc d, unsigned short* __restrict__ dst, long N4) {
  for (long i = blockIdx.x * (long)blockDim.x + threadIdx.x; i < N4;
       i += (long)gridDim.x * blockDim.x) {
    long e = i << 2;
    int seg = 0;
#pragma unroll
    for (int j = 1; j < 10; ++j) seg += (e >= d.cum[j]) ? 1 : 0;
    const float* s = d.s[seg];
    long off = e - d.cum[seg];
    float4 v = *reinterpret_cast<const float4*>(s + off);
    ushort4 o;
    o.x = f2bf(v.x); o.y = f2bf(v.y); o.z = f2bf(v.z); o.w = f2bf(v.w);
    *reinterpret_cast<ushort4*>(dst + e) = o;
  }
}

// ---------- transpose-cast: fp32 [R,C] -> bf16 [C,R], batched over z ----------
__global__ __launch_bounds__(256)
void tcast_kernel(const float* __restrict__ in, unsigned short* __restrict__ out,
                  int R, int C, long sIn, long sOut) {
  __shared__ float tile[64][65];
  int z = blockIdx.z;
  const float* src = in + (long)z * sIn;
  unsigned short* dst = out + (long)z * sOut;
  int r0 = blockIdx.y * 64, c0 = blockIdx.x * 64;
  int t = threadIdx.x;
  int lr = t >> 4;          // 0..15
  int lc = (t & 15) * 4;    // 0,4,..,60
#pragma unroll
  for (int j = 0; j < 4; ++j) {
    int r = lr + j * 16;
    float4 v = *reinterpret_cast<const float4*>(src + (long)(r0 + r) * C + c0 + lc);
    tile[r][lc] = v.x; tile[r][lc + 1] = v.y; tile[r][lc + 2] = v.z; tile[r][lc + 3] = v.w;
  }
  __syncthreads();
#pragma unroll
  for (int j = 0; j < 4; ++j) {
    int oc = lr + j * 16;
    ushort4 o;
    o.x = f2bf(tile[lc][oc]);
    o.y = f2bf(tile[lc + 1][oc]);
    o.z = f2bf(tile[lc + 2][oc]);
    o.w = f2bf(tile[lc + 3][oc]);
    *reinterpret_cast<ushort4*>(dst + (long)(c0 + oc) * R + r0 + lc) = o;
  }
}

// ---------- fused 4-branch transpose-cast: emb_i [1024,C_i] -> concat^T [960,1024] ----------
// x-tile -> branch: {0}=br0, {1,2}=br1, {3..6}=br2, {7..14}=br3 (1+2+4+8 = 15 tiles of 64 cols).
struct T4Desc { const float* src[4]; };

__global__ __launch_bounds__(256)
void tcast4_kernel(T4Desc d, unsigned short* __restrict__ out) {
  __shared__ float tile[64][65];
  const int Cb_[4] = {64, 128, 256, 512};
  const int xo_[4] = {0, 1, 3, 7};
  const int g0_[4] = {0, 64, 192, 448};
  int x = blockIdx.x;
  int br = (x >= 7) ? 3 : (x >= 3) ? 2 : (x >= 1) ? 1 : 0;
  int C = Cb_[br];
  int c0loc = (x - xo_[br]) * 64;
  int c0glob = g0_[br] + c0loc;
  int z = blockIdx.z;
  const float* src = d.src[br] + (long)z * 1024 * C;
  unsigned short* dst = out + (long)z * 983040;
  int r0 = blockIdx.y * 64;
  int t = threadIdx.x;
  int lr = t >> 4;
  int lc = (t & 15) * 4;
#pragma unroll
  for (int j = 0; j < 4; ++j) {
    int r = lr + j * 16;
    float4 v = *reinterpret_cast<const float4*>(src + (long)(r0 + r) * C + c0loc + lc);
    tile[r][lc] = v.x; tile[r][lc + 1] = v.y; tile[r][lc + 2] = v.z; tile[r][lc + 3] = v.w;
  }
  __syncthreads();
#pragma unroll
  for (int j = 0; j < 4; ++j) {
    int oc = lr + j * 16;
    ushort4 o;
    o.x = f2bf(tile[lc][oc]);
    o.y = f2bf(tile[lc + 1][oc]);
    o.z = f2bf(tile[lc + 2][oc]);
    o.w = f2bf(tile[lc + 3][oc]);
    *reinterpret_cast<ushort4*>(dst + (long)(c0glob + oc) * 1024 + r0 + lc) = o;
  }
}

// ---------- y-tile descriptor for branch-aligned tiling ----------
struct YDesc { int m0[8]; int mw[8]; int br[8]; };

// ---------- generic NT bf16 MFMA GEMM, TM x TN tile, 256 threads ----------
// 2-phase double-buffered staging (r5-proven best): issue next K-step's
// global_load_lds BEFORE computing current; single __syncthreads per step.
// LDS cells bank-swizzled (see swz_slot). nInner folds a reduction (heads)
// by walking A/B base pointers by iA/iB every K cols.
// [r6: depth-2 counted-vmcnt + 4 buffers REGRESSED (occupancy). m131/m132.]
template<int TM, int TN, int OUT, int DO_STATS, int YD>
__global__ __launch_bounds__(256)
void gemm_nt(const unsigned short* __restrict__ A,
             const unsigned short* __restrict__ B,
             void* __restrict__ Cp,
             int K, int lda, int ldb, long ldc, int Hdiv,
             long sAb, long sAh, long sBb, long sBh, long sC,
             int nInner, long iA, long iB,
             float alpha, float* __restrict__ stats,
             int Mclamp, int Nclamp, int Mwrite, int Nwrite, int Nvalid, YDesc yd) {
  constexpr int WM = TM / 32, WN = TN / 32;
  __shared__ unsigned short As[2][TM * 32];
  __shared__ unsigned short Bs[2][TN * 32];
  __shared__ float red[8];

  unsigned bxu, byu, bzu;
  xcd_swizzle(bxu, byu, bzu);
  int z = (int)bzu;
  int b = z / Hdiv, h = z % Hdiv;
  const unsigned short* Ab = A + (long)b * sAb + (long)h * sAh;
  const unsigned short* Bb = B + (long)b * sBb + (long)h * sBh;
  int y = (int)byu;
  int m0 = YD ? yd.m0[y] : y * TM;
  int rowLimit = YD ? (m0 + yd.mw[y]) : Mwrite;
  int n0 = (int)bxu * TN;
  int t = threadIdx.x;
  int lane = t & 63, wave = t >> 6;
  int wm = (wave >> 1) * (TM / 2), wn = (wave & 1) * (TN / 2);
  int l15 = lane & 15, q = lane >> 4;
  // pre-swizzled source column (write side of the LDS bank swizzle)
  int acol = ((t & 3) ^ ((t >> 3) & 3)) * 8;

  int arow = t >> 2;
  int rA[TM / 64], rB[TN / 64];
#pragma unroll
  for (int r = 0; r < TM / 64; ++r) rA[r] = min(m0 + r * 64 + arow, Mclamp - 1);
#pragma unroll
  for (int r = 0; r < TN / 64; ++r) rB[r] = min(n0 + r * 64 + arow, Nclamp - 1);

  int kSteps = K >> 5;
  int nt = nInner * kSteps;
  const unsigned short* Asrc = Ab;
  const unsigned short* Bsrc = Bb;
  int kk = 0;

  auto stage = [&](int bufSel) {
#pragma unroll
    for (int r = 0; r < TM / 64; ++r)
      __builtin_amdgcn_global_load_lds(
          (const __attribute__((address_space(1))) void*)(Asrc + (long)rA[r] * lda + acol + kk),
          (__attribute__((address_space(3))) void*)(&As[bufSel][r * 2048 + t * 8]), 16, 0, 0);
#pragma unroll
    for (int r = 0; r < TN / 64; ++r)
      __builtin_amdgcn_global_load_lds(
          (const __attribute__((address_space(1))) void*)(Bsrc + (long)rB[r] * ldb + acol + kk),
          (__attribute__((address_space(3))) void*)(&Bs[bufSel][r * 2048 + t * 8]), 16, 0, 0);
  };
  auto advance = [&]() { kk += 32; if (kk >= K) { kk = 0; Asrc += iA; Bsrc += iB; } };

  f32x4 acc[WM][WN] = {};
  stage(0);
  advance();
  __syncthreads();
  for (int s = 0; s < nt; ++s) {
    int cur = s & 1;
    if (s + 1 < nt) { stage(cur ^ 1); advance(); }
    short8 af[WM], bfr[WN];
#pragma unroll
    for (int i = 0; i < WM; ++i) {
      int row = wm + i * 16 + l15;
      af[i] = *reinterpret_cast<const short8*>(&As[cur][row * 32 + swz_slot(row, q) * 8]);
    }
#pragma unroll
    for (int j = 0; j < WN; ++j) {
      int row = wn + j * 16 + l15;
      bfr[j] = *reinterpret_cast<const short8*>(&Bs[cur][row * 32 + swz_slot(row, q) * 8]);
    }
#pragma unroll
    for (int i = 0; i < WM; ++i)
#pragma unroll
      for (int j = 0; j < WN; ++j)
        acc[i][j] = __builtin_amdgcn_mfma_f32_16x16x32_bf16(af[i], bfr[j], acc[i][j], 0, 0, 0);
    __syncthreads();
  }

  long cbase = (long)z * sC;
  float ssum = 0.f, ssq = 0.f;
#pragma unroll
  for (int i = 0; i < WM; ++i)
#pragma unroll
    for (int j = 0; j < WN; ++j)
#pragma unroll
      for (int r = 0; r < 4; ++r) {
        float v = acc[i][j][r] * alpha;
        int rg = m0 + wm + i * 16 + q * 4 + r;
        int cg = n0 + wn + j * 16 + l15;
        if (rg < rowLimit && cg < Nwrite) {
          long idx = cbase + (long)rg * ldc + cg;
          if (OUT == 1) ((float*)Cp)[idx] = v;
          else if (OUT == 2) ((_Float16*)Cp)[idx] = (_Float16)v;
          else ((unsigned short*)Cp)[idx] = f2bf(v);
        }
        if (DO_STATS && rg < rowLimit && cg < Nvalid) { ssum += v; ssq += v * v; }
      }

  if (DO_STATS) {
#pragma unroll
    for (int o = 32; o; o >>= 1) {
      ssum += __shfl_down(ssum, o, 64);
      ssq  += __shfl_down(ssq,  o, 64);
    }
    if (lane == 0) { red[wave] = ssum; red[wave + 4] = ssq; }
    __syncthreads();
    if (t == 0) {
      long slot = YD ? ((long)z * 8 + yd.br[y] * 2) : ((long)z * 2);
      atomicAdd(stats + slot,     red[0] + red[1] + red[2] + red[3]);
      atomicAdd(stats + slot + 1, red[4] + red[5] + red[6] + red[7]);
    }
  }
}

// ---------- block-diagonal A GEMM: T[b,h] = Wq_br[h] @ G[b] (per y-tile branch) ----------
struct BDesc { int K[8]; int aRow0[8]; int out0[8]; int mw[8]; int bc[8]; long aOff[8]; long aH[8]; };

__global__ __launch_bounds__(256)
void gemm_bd(const unsigned short* __restrict__ A0,
             const unsigned short* __restrict__ B0,
             unsigned short* __restrict__ Cp,
             int ldb, long sBz, long sC, BDesc d) {
  constexpr int TM = 128, TN = 64, WM = 4, WN = 2;
  __shared__ unsigned short As[2][TM * 32];
  __shared__ unsigned short Bs[2][TN * 32];
  unsigned bxu, byu, bzu;
  xcd_swizzle(bxu, byu, bzu);
  int z = (int)bzu;
  int b = z >> 2, h = z & 3;
  int y = (int)byu;
  int K = d.K[y];
  const unsigned short* Ab = A0 + d.aOff[y] + (long)h * d.aH[y];
  const unsigned short* Bb = B0 + (long)b * sBz + d.bc[y];
  int n0 = (int)bxu * TN;
  int t = threadIdx.x;
  int lane = t & 63, wave = t >> 6;
  int wm = (wave >> 1) * 64, wn = (wave & 1) * 32;
  int l15 = lane & 15, q = lane >> 4;
  int arow = t >> 2;
  int acol = ((t & 3) ^ ((t >> 3) & 3)) * 8;

  int rA0 = min(d.aRow0[y] + arow, K - 1);
  int rA1 = min(d.aRow0[y] + 64 + arow, K - 1);
  int rB0 = n0 + arow;

  int kk = 0;
  auto stage = [&](int bufSel) {
    __builtin_amdgcn_global_load_lds(
        (const __attribute__((address_space(1))) void*)(Ab + (long)rA0 * K + acol + kk),
        (__attribute__((address_space(3))) void*)(&As[bufSel][t * 8]), 16, 0, 0);
    __builtin_amdgcn_global_load_lds(
        (const __attribute__((address_space(1))) void*)(Ab + (long)rA1 * K + acol + kk),
        (__attribute__((address_space(3))) void*)(&As[bufSel][2048 + t * 8]), 16, 0, 0);
    __builtin_amdgcn_global_load_lds(
        (const __attribute__((address_space(1))) void*)(Bb + (long)rB0 * ldb + acol + kk),
        (__attribute__((address_space(3))) void*)(&Bs[bufSel][t * 8]), 16, 0, 0);
  };

  int nt = K >> 5;
  f32x4 acc[WM][WN] = {};
  stage(0);
  kk += 32;
  __syncthreads();
  for (int s = 0; s < nt; ++s) {
    int cur = s & 1;
    if (s + 1 < nt) { stage(cur ^ 1); kk += 32; }
    short8 af[WM], bfr[WN];
#pragma unroll
    for (int i = 0; i < WM; ++i) {
      int row = wm + i * 16 + l15;
      af[i] = *reinterpret_cast<const short8*>(&As[cur][row * 32 + swz_slot(row, q) * 8]);
    }
#pragma unroll
    for (int j = 0; j < WN; ++j) {
      int row = wn + j * 16 + l15;
      bfr[j] = *reinterpret_cast<const short8*>(&Bs[cur][row * 32 + swz_slot(row, q) * 8]);
    }
#pragma unroll
    for (int i = 0; i < WM; ++i)
#pragma unroll
      for (int j = 0; j < WN; ++j)
        acc[i][j] = __builtin_amdgcn_mfma_f32_16x16x32_bf16(af[i], bfr[j], acc[i][j], 0, 0, 0);
    __syncthreads();
  }

  long cbase = (long)z * sC;
  int mw = d.mw[y], out0 = d.out0[y];
#pragma unroll
  for (int i = 0; i < WM; ++i)
#pragma unroll
    for (int j = 0; j < WN; ++j)
#pragma unroll
      for (int r = 0; r < 4; ++r) {
        int loc = wm + i * 16 + q * 4 + r;
        int cg = n0 + wn + j * 16 + l15;
        if (loc < mw) {
          long idx = cbase + (long)(out0 + loc) * 960 + cg;
          Cp[idx] = f2bf(acc[i][j][r]);
        }
      }
}

// ---------- instance-norm + softmax over KV=960, in-place fp16 -> bf16 ----------
__global__ __launch_bounds__(256)
void norm_softmax_all(_Float16* __restrict__ S, const float* __restrict__ stats) {
  long row = blockIdx.x;            // z*960 + cc
  int z = (int)(row / 960), cc = (int)(row % 960);
  int br = (cc < 64) ? 0 : (cc < 192) ? 1 : (cc < 448) ? 2 : 3;
  int Cbr = (br == 0) ? 64 : (br == 1) ? 128 : (br == 2) ? 256 : 512;
  float invCnt = 1.0f / ((float)Cbr * 960.0f);
  float m1 = stats[z * 8 + br * 2 + 0] * invCnt;
  float m2 = stats[z * 8 + br * 2 + 1] * invCnt;
  float rsig = rsqrtf(m2 - m1 * m1 + 1e-5f);
  _Float16* s = S + row * 960;
  int t = threadIdx.x;
  float e[4]; float acc = 0.f;
#pragma unroll
  for (int j = 0; j < 4; ++j) {
    int i = t + j * 256;
    if (i < 960) { e[j] = __expf(((float)s[i] - m1) * rsig); acc += e[j]; }
    else e[j] = 0.f;
  }
#pragma unroll
  for (int o = 32; o; o >>= 1) acc += __shfl_down(acc, o, 64);
  __shared__ float red[4];
  if ((t & 63) == 0) red[t >> 6] = acc;
  __syncthreads();
  float inv = 1.0f / (red[0] + red[1] + red[2] + red[3]);
  unsigned short* p = (unsigned short*)s;
#pragma unroll
  for (int j = 0; j < 4; ++j) {
    int i = t + j * 256;
    if (i < 960) p[i] = f2bf(e[j] * inv);
  }
}

// ---------- 4-branch batched NT GEMM (out-proj), branch from bx ----------
struct MDesc {
  long aOff[4], bOff[4], cOff[4];
  long sAz[4], sBz[4], sCz[4];
  long iA[4], iB[4];
  int  lda[4], ldb[4], ldcv[4];
  int  Kk[4], Ncl[4], nIn[4];
  int  nstart[4];
  float alpha[4];
};

template<int OUT_F32>
__global__ __launch_bounds__(256)
void gemm_multi(const unsigned short* __restrict__ A0,
                const unsigned short* __restrict__ B0,
                void* __restrict__ Cp, MDesc d) {
  __shared__ unsigned short As[2][128 * 32];
  __shared__ unsigned short Bs[2][128 * 32];
  unsigned bxu, byu, bzu;
  xcd_swizzle(bxu, byu, bzu);
  int bx = (int)bxu;
  int br = (bx >= d.nstart[3]) ? 3 : (bx >= d.nstart[2]) ? 2 : (bx >= d.nstart[1]) ? 1 : 0;
  int z = (int)bzu;
  int n0 = (bx - d.nstart[br]) * 128;
  int m0 = (int)byu * 128;
  int K = d.Kk[br], lda = d.lda[br], ldb = d.ldb[br], ldc = d.ldcv[br];
  int Ncl = d.Ncl[br], nInner = d.nIn[br];
  long iA = d.iA[br], iB = d.iB[br];
  float alpha = d.alpha[br];
  const unsigned short* Ab = A0 + d.aOff[br] + (long)z * d.sAz[br];
  const unsigned short* Bb = B0 + d.bOff[br] + (long)z * d.sBz[br];

  int t = threadIdx.x, lane = t & 63, wave = t >> 6;
  int wm = (wave >> 1) * 64, wn = (wave & 1) * 64;
  int l15 = lane & 15, q = lane >> 4;
  int arow = t >> 2;
  int acol = ((t & 3) ^ ((t >> 3) & 3)) * 8;
  int rA0 = m0 + arow, rA1 = m0 + 64 + arow;
  int rB0 = min(n0 + arow, Ncl - 1), rB1 = min(n0 + 64 + arow, Ncl - 1);

  const unsigned short* Asrc = Ab;
  const unsigned short* Bsrc = Bb;
  int kk = 0;
  auto stage = [&](int bufSel) {
    __builtin_amdgcn_global_load_lds(
        (const __attribute__((address_space(1))) void*)(Asrc + (long)rA0 * lda + acol + kk),
        (__attribute__((address_space(3))) void*)(&As[bufSel][t * 8]), 16, 0, 0);
    __builtin_amdgcn_global_load_lds(
        (const __attribute__((address_space(1))) void*)(Asrc + (long)rA1 * lda + acol + kk),
        (__attribute__((address_space(3))) void*)(&As[bufSel][2048 + t * 8]), 16, 0, 0);
    __builtin_amdgcn_global_load_lds(
        (const __attribute__((address_space(1))) void*)(Bsrc + (long)rB0 * ldb + acol + kk),
        (__attribute__((address_space(3))) void*)(&Bs[bufSel][t * 8]), 16, 0, 0);
    __builtin_amdgcn_global_load_lds(
        (const __attribute__((address_space(1))) void*)(Bsrc + (long)rB1 * ldb + acol + kk),
        (__attribute__((address_space(3))) void*)(&Bs[bufSel][2048 + t * 8]), 16, 0, 0);
  };
  auto advance = [&]() { kk += 32; if (kk >= K) { kk = 0; Asrc += iA; Bsrc += iB; } };

  int nt = nInner * (K >> 5);
  f32x4 acc[4][4] = {};
  stage(0);
  advance();
  __syncthreads();
  for (int s = 0; s < nt; ++s) {
    int cur = s & 1;
    if (s + 1 < nt) { stage(cur ^ 1); advance(); }
    short8 af[4], bfr[4];
#pragma unroll
    for (int i = 0; i < 4; ++i) {
      int row = wm + i * 16 + l15;
      af[i] = *reinterpret_cast<const short8*>(&As[cur][row * 32 + swz_slot(row, q) * 8]);
    }
#pragma unroll
    for (int j = 0; j < 4; ++j) {
      int row = wn + j * 16 + l15;
      bfr[j] = *reinterpret_cast<const short8*>(&Bs[cur][row * 32 + swz_slot(row, q) * 8]);
    }
#pragma unroll
    for (int i = 0; i < 4; ++i)
#pragma unroll
      for (int j = 0; j < 4; ++j)
        acc[i][j] = __builtin_amdgcn_mfma_f32_16x16x32_bf16(af[i], bfr[j], acc[i][j], 0, 0, 0);
    __syncthreads();
  }

  long cb = d.cOff[br] + (long)z * d.sCz[br];
#pragma unroll
  for (int i = 0; i < 4; ++i)
#pragma unroll
    for (int j = 0; j < 4; ++j)
#pragma unroll
      for (int r = 0; r < 4; ++r) {
        float v = acc[i][j][r] * alpha;
        int rg = m0 + wm + i * 16 + q * 4 + r;
        int cg = n0 + wn + j * 16 + l15;
        if (cg < Ncl) {
          long idx = cb + (long)rg * ldc + cg;
          if (OUT_F32) ((float*)Cp)[idx] = v;
          else ((unsigned short*)Cp)[idx] = f2bf(v);
        }
      }
}

// ---------- host ----------
extern "C" void kernel_launch(void* const* d_in, const int* in_sizes, int n_in,
                              void* d_out, int out_size, void* d_ws, size_t ws_size,
                              hipStream_t stream) {
  const float* embs[4] = {(const float*)d_in[0], (const float*)d_in[1],
                          (const float*)d_in[2], (const float*)d_in[3]};
  const float* embA = (const float*)d_in[4];
  const float* Wk   = (const float*)d_in[9];
  const float* Wv   = (const float*)d_in[10];
  float* out = (float*)d_out;

  char* base = (char*)d_ws;
  size_t off = 0;
  auto take = [&](size_t bytes) -> void* {
    void* p = base + off;
    off += (bytes + 255) & ~(size_t)255;
    return p;
  };
  // contiguous cast destination region: EA | WQb | WKb | WOb (all 256B-multiples)
  unsigned short* EA    = (unsigned short*)take(15728640);  // embA bf16 [8][1024][960]
  unsigned short* WQb   = (unsigned short*)take(2785280);   // Wq1..4 bf16
  unsigned short* WKb   = (unsigned short*)take(7372800);   // Wk bf16 [4][960][960]
  unsigned short* WOb   = (unsigned short*)take(696320);    // Wo1..4 bf16
  unsigned short* embAT = (unsigned short*)take(15728640);  // embA^T [8][960][1024]; CT aliases
  unsigned short* embTc = (unsigned short*)take(15728640);  // concat emb^T [8][960][1024]
  unsigned short* WvT   = (unsigned short*)take(7372800);   // Wv^T [4][960][960]
  float*          ST    = (float*)take(1024);               // stats [32][4][2] f32
  unsigned short* GT    = (unsigned short*)take(14745600);  // G [8][960][960]; SPW aliases
  unsigned short* Tbuf  = (unsigned short*)take(58982400);  // T [32][960][960]
  char*           SCr   = (char*)take(58982400);            // scores fp16 -> probs bf16 in place
  _Float16*       SC    = (_Float16*)SCr;
  unsigned short* PR    = (unsigned short*)SCr;             // probs bf16 [32][960][960]
  unsigned short* SPW   = GT;                               // [8][960][960]  (G dead after T)
  unsigned short* CT    = embAT;                            // [8][1024][960] (embAT dead after G)

  if (ws_size < off) return;  // fail clean instead of faulting

  hipMemsetAsync(ST, 0, 1024, stream);

  const long Cs[4]     = {64, 128, 256, 512};
  const long c0s[4]    = {0, 64, 192, 448};
  const long woOff[4]  = {0, 4096, 20480, 86016};
  const long outOff[4] = {0, 524288, 1572864, 3670016};
  const float kscale = 0.0322748612f;  // 1/sqrt(960)
  YDesc ydDummy = {};

  // one fused cast for all plain fp32->bf16 segments (dst = EA..WOb contiguous)
  {
    CastDesc cd;
    const float* ss[10] = {embA, (const float*)d_in[5], (const float*)d_in[6],
                           (const float*)d_in[7], (const float*)d_in[8], Wk,
                           (const float*)d_in[11], (const float*)d_in[12],
                           (const float*)d_in[13], (const float*)d_in[14]};
    const long ln[10] = {7864320, 16384, 65536, 262144, 1048576, 3686400,
                         4096, 16384, 65536, 262144};
    long c = 0;
    for (int i = 0; i < 10; ++i) { cd.s[i] = ss[i]; cd.cum[i] = c; c += ln[i]; }
    cd.cum[10] = c;
    castN_kernel<<<4096, 256, 0, stream>>>(cd, EA, c >> 2);
  }
  // transpose-casts (3 launches)
  tcast_kernel<<<dim3(15, 16, 8), 256, 0, stream>>>(embA, embAT, 1024, 960, 983040, 983040);
  {
    T4Desc td; for (int i = 0; i < 4; ++i) td.src[i] = embs[i];
    tcast4_kernel<<<dim3(15, 16, 8), 256, 0, stream>>>(td, embTc);
  }
  tcast_kernel<<<dim3(15, 15, 4), 256, 0, stream>>>(Wv, WvT, 960, 960, 921600, 921600);

  // G[b][k][c] = sum_n embA[n,k]*emb_cat[n,c] : M=960, N=960, K=1024, z=8 (512 blocks)
  gemm_nt<128, 128, 0, 0, 0><<<dim3(8, 8, 8), 256, 0, stream>>>(
      embAT, embTc, GT, 1024, 1024, 1024, 960, 1,
      983040L, 0L, 983040L, 0L, 921600L,
      1, 0L, 0L, 1.0f, nullptr, 960, 960, 960, 960, 0, ydDummy);

  // T[b,h][cc][k] = Wq_br[h] @ G[b] (block-diagonal over branch rows), one launch
  {
    BDesc d;
    const int brOf[8]  = {0, 1, 2, 2, 3, 3, 3, 3};
    const int ar0[8]   = {0, 0, 0, 128, 0, 128, 256, 384};
    const long wqOff[4] = {0, 16384, 81920, 344064};
    for (int y = 0; y < 8; ++y) {
      int br = brOf[y];
      int Ci = (int)Cs[br];
      d.K[y] = Ci;
      d.aRow0[y] = ar0[y];
      d.out0[y] = (int)c0s[br] + ar0[y];
      d.mw[y] = (br == 0) ? 64 : 128;
      d.bc[y] = (int)c0s[br];
      d.aOff[y] = wqOff[br];
      d.aH[y] = (long)Ci * Ci;
    }
    gemm_bd<<<dim3(15, 8, 32), 256, 0, stream>>>(WQb, GT, Tbuf, 960, 921600L, 921600L, d);
  }

  // scores[b,h][cc][o] = kscale * T[b,h] @ Wk[h]^T, fp16 out + per-branch stats (2048 blocks)
  {
    YDesc yd;
    const int m0s[8] = {0, 64, 192, 320, 448, 576, 704, 832};
    const int mws[8] = {64, 128, 128, 128, 128, 128, 128, 128};
    const int brs[8] = {0, 1, 2, 2, 3, 3, 3, 3};
    for (int y = 0; y < 8; ++y) { yd.m0[y] = m0s[y]; yd.mw[y] = mws[y]; yd.br[y] = brs[y]; }
    gemm_nt<128, 128, 2, 1, 1><<<dim3(8, 8, 32), 256, 0, stream>>>(
        Tbuf, WKb, SC, 960, 960, 960, 960, 4,
        3686400L, 921600L, 0L, 921600L, 921600L,
        1, 0L, 0L, kscale, ST, 960, 960, 960, 960, 960, yd);
  }

  // instance-norm + softmax, in place (fp16 scores -> bf16 probs), one launch
  norm_softmax_all<<<dim3(32 * 960), 256, 0, stream>>>(SC, ST);

  // SPW[b][cc][k] = 0.25 * sum_h probs[b,h] @ WvT[h] : z=8, nInner=4 (512 blocks)
  gemm_nt<128, 128, 0, 0, 0><<<dim3(8, 8, 8), 256, 0, stream>>>(
      PR, WvT, SPW, 960, 960, 960, 960, 1,
      3686400L, 0L, 0L, 0L, 921600L,
      4, 921600L, 921600L, 0.25f, nullptr, 960, 960, 960, 960, 0, ydDummy);

  // CT[b][n][cc] = embA[b] @ SPW[b]^T : M=1024, N=960, K=960, z=8 (512 blocks)
  gemm_nt<128, 128, 0, 0, 0><<<dim3(8, 8, 8), 256, 0, stream>>>(
      EA, SPW, CT, 960, 960, 960, 960, 1,
      983040L, 0L, 921600L, 0L, 983040L,
      1, 0L, 0L, 1.0f, nullptr, 1024, 960, 1024, 960, 0, ydDummy);

  // out-all: out[b,n,c'] = CT[b][:, branch cols] @ Wo^T, one launch (512 blocks)
  {
    MDesc d;
    for (int i = 0; i < 4; ++i) {
      long C = Cs[i];
      d.aOff[i] = c0s[i];       d.sAz[i] = 983040L;          d.iA[i] = 0;
      d.bOff[i] = woOff[i];     d.sBz[i] = 0;                d.iB[i] = 0;
      d.cOff[i] = outOff[i];    d.sCz[i] = 1024L * C;
      d.lda[i] = 960; d.ldb[i] = (int)C; d.ldcv[i] = (int)C;
      d.Kk[i] = (int)C; d.Ncl[i] = (int)C; d.nIn[i] = 1;
      d.alpha[i] = 1.0f;
    }
    d.nstart[0] = 0; d.nstart[1] = 1; d.nstart[2] = 2; d.nstart[3] = 4;
    gemm_multi<1><<<dim3(8, 8, 8), 256, 0, stream>>>(CT, WOb, out, d);
  }
  (void)in_sizes; (void)n_in; (void)out_size;
}

// Round 9
// 483.264 us; speedup vs baseline: 1.0624x; 1.0414x over previous
//
#include <hip/hip_runtime.h>
#include <hip/hip_bf16.h>

// ---------- types ----------
typedef __attribute__((ext_vector_type(8))) short short8;
typedef __attribute__((ext_vector_type(4))) float f32x4;

static __device__ __forceinline__ unsigned short f2bf(float x) {
  union { __hip_bfloat16 h; unsigned short u; } cv;
  cv.h = __float2bfloat16(x);
  return cv.u;
}

// XCD-chunked swizzle (T1): contiguous logical-tile ranges per XCD (nwg%8==0).
// Verified r3->r4: FETCH 545MB -> 65MB on the scores/SPW GEMMs.
static __device__ __forceinline__ void xcd_swizzle(unsigned& bx, unsigned& by, unsigned& bz) {
  unsigned nwg = gridDim.x * gridDim.y * gridDim.z;
  unsigned lin = blockIdx.x + gridDim.x * (blockIdx.y + gridDim.y * blockIdx.z);
  unsigned chunk = nwg >> 3;
  lin = (lin & 7) * chunk + (lin >> 3);
  bx = lin % gridDim.x;
  unsigned tmp = lin / gridDim.x;
  by = tmp % gridDim.y;
  bz = tmp / gridDim.y;
}

// LDS bank swizzle (T2, BK=32, both-sides per rule #21). r8 verified:
// SQ_LDS_BANK_CONFLICT 7.86M -> 0. Helped z=8 latency-exposed GEMMs (~24us),
// neutral-to-negative on the 2048-block scores launch -> per-launch SWZ flag.
static __device__ __forceinline__ int swz_slot(int row, int q) {
  return q ^ ((row >> 1) & 3);
}

// ---------- cast fp32 -> bf16 over up to 10 concatenated segments ----------
struct CastDesc { const float* s[10]; long cum[11]; };

__global__ void castN_kernel(CastDesc d, unsigned short* __restrict__ dst, long N4) {
  for (long i = blockIdx.x * (long)blockDim.x + threadIdx.x; i < N4;
       i += (long)gridDim.x * blockDim.x) {
    long e = i << 2;
    int seg = 0;
#pragma unroll
    for (int j = 1; j < 10; ++j) seg += (e >= d.cum[j]) ? 1 : 0;
    const float* s = d.s[seg];
    long off = e - d.cum[seg];
    float4 v = *reinterpret_cast<const float4*>(s + off);
    ushort4 o;
    o.x = f2bf(v.x); o.y = f2bf(v.y); o.z = f2bf(v.z); o.w = f2bf(v.w);
    *reinterpret_cast<ushort4*>(dst + e) = o;
  }
}

// ---------- transpose-cast: fp32 [R,C] -> bf16 [C,R], batched over z ----------
__global__ __launch_bounds__(256)
void tcast_kernel(const float* __restrict__ in, unsigned short* __restrict__ out,
                  int R, int C, long sIn, long sOut) {
  __shared__ float tile[64][65];
  int z = blockIdx.z;
  const float* src = in + (long)z * sIn;
  unsigned short* dst = out + (long)z * sOut;
  int r0 = blockIdx.y * 64, c0 = blockIdx.x * 64;
  int t = threadIdx.x;
  int lr = t >> 4;          // 0..15
  int lc = (t & 15) * 4;    // 0,4,..,60
#pragma unroll
  for (int j = 0; j < 4; ++j) {
    int r = lr + j * 16;
    float4 v = *reinterpret_cast<const float4*>(src + (long)(r0 + r) * C + c0 + lc);
    tile[r][lc] = v.x; tile[r][lc + 1] = v.y; tile[r][lc + 2] = v.z; tile[r][lc + 3] = v.w;
  }
  __syncthreads();
#pragma unroll
  for (int j = 0; j < 4; ++j) {
    int oc = lr + j * 16;
    ushort4 o;
    o.x = f2bf(tile[lc][oc]);
    o.y = f2bf(tile[lc + 1][oc]);
    o.z = f2bf(tile[lc + 2][oc]);
    o.w = f2bf(tile[lc + 3][oc]);
    *reinterpret_cast<ushort4*>(dst + (long)(c0 + oc) * R + r0 + lc) = o;
  }
}

// ---------- fused 4-branch transpose-cast: emb_i [1024,C_i] -> concat^T [960,1024] ----------
struct T4Desc { const float* src[4]; };

__global__ __launch_bounds__(256)
void tcast4_kernel(T4Desc d, unsigned short* __restrict__ out) {
  __shared__ float tile[64][65];
  const int Cb_[4] = {64, 128, 256, 512};
  const int xo_[4] = {0, 1, 3, 7};
  const int g0_[4] = {0, 64, 192, 448};
  int x = blockIdx.x;
  int br = (x >= 7) ? 3 : (x >= 3) ? 2 : (x >= 1) ? 1 : 0;
  int C = Cb_[br];
  int c0loc = (x - xo_[br]) * 64;
  int c0glob = g0_[br] + c0loc;
  int z = blockIdx.z;
  const float* src = d.src[br] + (long)z * 1024 * C;
  unsigned short* dst = out + (long)z * 983040;
  int r0 = blockIdx.y * 64;
  int t = threadIdx.x;
  int lr = t >> 4;
  int lc = (t & 15) * 4;
#pragma unroll
  for (int j = 0; j < 4; ++j) {
    int r = lr + j * 16;
    float4 v = *reinterpret_cast<const float4*>(src + (long)(r0 + r) * C + c0loc + lc);
    tile[r][lc] = v.x; tile[r][lc + 1] = v.y; tile[r][lc + 2] = v.z; tile[r][lc + 3] = v.w;
  }
  __syncthreads();
#pragma unroll
  for (int j = 0; j < 4; ++j) {
    int oc = lr + j * 16;
    ushort4 o;
    o.x = f2bf(tile[lc][oc]);
    o.y = f2bf(tile[lc + 1][oc]);
    o.z = f2bf(tile[lc + 2][oc]);
    o.w = f2bf(tile[lc + 3][oc]);
    *reinterpret_cast<ushort4*>(dst + (long)(c0glob + oc) * 1024 + r0 + lc) = o;
  }
}

// ---------- y-tile descriptor for branch-aligned tiling ----------
struct YDesc { int m0[8]; int mw[8]; int br[8]; };

// ---------- generic NT bf16 MFMA GEMM, TM x TN tile, 256 threads ----------
// 2-phase double-buffered staging (r5-proven best). SWZ selects the LDS bank
// swizzle (r8: helps latency-exposed z=8 launches, not the 2048-block scores).
template<int TM, int TN, int OUT, int DO_STATS, int YD, int SWZ>
__global__ __launch_bounds__(256)
void gemm_nt(const unsigned short* __restrict__ A,
             const unsigned short* __restrict__ B,
             void* __restrict__ Cp,
             int K, int lda, int ldb, long ldc, int Hdiv,
             long sAb, long sAh, long sBb, long sBh, long sC,
             int nInner, long iA, long iB,
             float alpha, float* __restrict__ stats,
             int Mclamp, int Nclamp, int Mwrite, int Nwrite, int Nvalid, YDesc yd) {
  constexpr int WM = TM / 32, WN = TN / 32;
  __shared__ unsigned short As[2][TM * 32];
  __shared__ unsigned short Bs[2][TN * 32];
  __shared__ float red[8];

  unsigned bxu, byu, bzu;
  xcd_swizzle(bxu, byu, bzu);
  int z = (int)bzu;
  int b = z / Hdiv, h = z % Hdiv;
  const unsigned short* Ab = A + (long)b * sAb + (long)h * sAh;
  const unsigned short* Bb = B + (long)b * sBb + (long)h * sBh;
  int y = (int)byu;
  int m0 = YD ? yd.m0[y] : y * TM;
  int rowLimit = YD ? (m0 + yd.mw[y]) : Mwrite;
  int n0 = (int)bxu * TN;
  int t = threadIdx.x;
  int lane = t & 63, wave = t >> 6;
  int wm = (wave >> 1) * (TM / 2), wn = (wave & 1) * (TN / 2);
  int l15 = lane & 15, q = lane >> 4;
  int acol = SWZ ? ((t & 3) ^ ((t >> 3) & 3)) * 8 : (t & 3) * 8;

  int arow = t >> 2;
  int rA[TM / 64], rB[TN / 64];
#pragma unroll
  for (int r = 0; r < TM / 64; ++r) rA[r] = min(m0 + r * 64 + arow, Mclamp - 1);
#pragma unroll
  for (int r = 0; r < TN / 64; ++r) rB[r] = min(n0 + r * 64 + arow, Nclamp - 1);

  int kSteps = K >> 5;
  int nt = nInner * kSteps;
  const unsigned short* Asrc = Ab;
  const unsigned short* Bsrc = Bb;
  int kk = 0;

  auto stage = [&](int bufSel) {
#pragma unroll
    for (int r = 0; r < TM / 64; ++r)
      __builtin_amdgcn_global_load_lds(
          (const __attribute__((address_space(1))) void*)(Asrc + (long)rA[r] * lda + acol + kk),
          (__attribute__((address_space(3))) void*)(&As[bufSel][r * 2048 + t * 8]), 16, 0, 0);
#pragma unroll
    for (int r = 0; r < TN / 64; ++r)
      __builtin_amdgcn_global_load_lds(
          (const __attribute__((address_space(1))) void*)(Bsrc + (long)rB[r] * ldb + acol + kk),
          (__attribute__((address_space(3))) void*)(&Bs[bufSel][r * 2048 + t * 8]), 16, 0, 0);
  };
  auto advance = [&]() { kk += 32; if (kk >= K) { kk = 0; Asrc += iA; Bsrc += iB; } };

  f32x4 acc[WM][WN] = {};
  stage(0);
  advance();
  __syncthreads();
  for (int s = 0; s < nt; ++s) {
    int cur = s & 1;
    if (s + 1 < nt) { stage(cur ^ 1); advance(); }
    short8 af[WM], bfr[WN];
#pragma unroll
    for (int i = 0; i < WM; ++i) {
      int row = wm + i * 16 + l15;
      int slot = SWZ ? swz_slot(row, q) : q;
      af[i] = *reinterpret_cast<const short8*>(&As[cur][row * 32 + slot * 8]);
    }
#pragma unroll
    for (int j = 0; j < WN; ++j) {
      int row = wn + j * 16 + l15;
      int slot = SWZ ? swz_slot(row, q) : q;
      bfr[j] = *reinterpret_cast<const short8*>(&Bs[cur][row * 32 + slot * 8]);
    }
#pragma unroll
    for (int i = 0; i < WM; ++i)
#pragma unroll
      for (int j = 0; j < WN; ++j)
        acc[i][j] = __builtin_amdgcn_mfma_f32_16x16x32_bf16(af[i], bfr[j], acc[i][j], 0, 0, 0);
    __syncthreads();
  }

  long cbase = (long)z * sC;
  float ssum = 0.f, ssq = 0.f;
#pragma unroll
  for (int i = 0; i < WM; ++i)
#pragma unroll
    for (int j = 0; j < WN; ++j)
#pragma unroll
      for (int r = 0; r < 4; ++r) {
        float v = acc[i][j][r] * alpha;
        int rg = m0 + wm + i * 16 + q * 4 + r;
        int cg = n0 + wn + j * 16 + l15;
        if (rg < rowLimit && cg < Nwrite) {
          long idx = cbase + (long)rg * ldc + cg;
          if (OUT == 1) ((float*)Cp)[idx] = v;
          else if (OUT == 2) ((_Float16*)Cp)[idx] = (_Float16)v;
          else ((unsigned short*)Cp)[idx] = f2bf(v);
        }
        if (DO_STATS && rg < rowLimit && cg < Nvalid) { ssum += v; ssq += v * v; }
      }

  if (DO_STATS) {
#pragma unroll
    for (int o = 32; o; o >>= 1) {
      ssum += __shfl_down(ssum, o, 64);
      ssq  += __shfl_down(ssq,  o, 64);
    }
    if (lane == 0) { red[wave] = ssum; red[wave + 4] = ssq; }
    __syncthreads();
    if (t == 0) {
      long slot = YD ? ((long)z * 8 + yd.br[y] * 2) : ((long)z * 2);
      atomicAdd(stats + slot,     red[0] + red[1] + red[2] + red[3]);
      atomicAdd(stats + slot + 1, red[4] + red[5] + red[6] + red[7]);
    }
  }
}

// ---------- block-diagonal A GEMM: T[b,h] = Wq_br[h] @ G[b] (per y-tile branch) ----------
struct BDesc { int K[8]; int aRow0[8]; int out0[8]; int mw[8]; int bc[8]; long aOff[8]; long aH[8]; };

__global__ __launch_bounds__(256)
void gemm_bd(const unsigned short* __restrict__ A0,
             const unsigned short* __restrict__ B0,
             unsigned short* __restrict__ Cp,
             int ldb, long sBz, long sC, BDesc d) {
  constexpr int TM = 128, TN = 64, WM = 4, WN = 2;
  __shared__ unsigned short As[2][TM * 32];
  __shared__ unsigned short Bs[2][TN * 32];
  unsigned bxu, byu, bzu;
  xcd_swizzle(bxu, byu, bzu);
  int z = (int)bzu;
  int b = z >> 2, h = z & 3;
  int y = (int)byu;
  int K = d.K[y];
  const unsigned short* Ab = A0 + d.aOff[y] + (long)h * d.aH[y];
  const unsigned short* Bb = B0 + (long)b * sBz + d.bc[y];
  int n0 = (int)bxu * TN;
  int t = threadIdx.x;
  int lane = t & 63, wave = t >> 6;
  int wm = (wave >> 1) * 64, wn = (wave & 1) * 32;
  int l15 = lane & 15, q = lane >> 4;
  int arow = t >> 2;
  int acol = ((t & 3) ^ ((t >> 3) & 3)) * 8;

  int rA0 = min(d.aRow0[y] + arow, K - 1);
  int rA1 = min(d.aRow0[y] + 64 + arow, K - 1);
  int rB0 = n0 + arow;

  int kk = 0;
  auto stage = [&](int bufSel) {
    __builtin_amdgcn_global_load_lds(
        (const __attribute__((address_space(1))) void*)(Ab + (long)rA0 * K + acol + kk),
        (__attribute__((address_space(3))) void*)(&As[bufSel][t * 8]), 16, 0, 0);
    __builtin_amdgcn_global_load_lds(
        (const __attribute__((address_space(1))) void*)(Ab + (long)rA1 * K + acol + kk),
        (__attribute__((address_space(3))) void*)(&As[bufSel][2048 + t * 8]), 16, 0, 0);
    __builtin_amdgcn_global_load_lds(
        (const __attribute__((address_space(1))) void*)(Bb + (long)rB0 * ldb + acol + kk),
        (__attribute__((address_space(3))) void*)(&Bs[bufSel][t * 8]), 16, 0, 0);
  };

  int nt = K >> 5;
  f32x4 acc[WM][WN] = {};
  stage(0);
  kk += 32;
  __syncthreads();
  for (int s = 0; s < nt; ++s) {
    int cur = s & 1;
    if (s + 1 < nt) { stage(cur ^ 1); kk += 32; }
    short8 af[WM], bfr[WN];
#pragma unroll
    for (int i = 0; i < WM; ++i) {
      int row = wm + i * 16 + l15;
      af[i] = *reinterpret_cast<const short8*>(&As[cur][row * 32 + swz_slot(row, q) * 8]);
    }
#pragma unroll
    for (int j = 0; j < WN; ++j) {
      int row = wn + j * 16 + l15;
      bfr[j] = *reinterpret_cast<const short8*>(&Bs[cur][row * 32 + swz_slot(row, q) * 8]);
    }
#pragma unroll
    for (int i = 0; i < WM; ++i)
#pragma unroll
      for (int j = 0; j < WN; ++j)
        acc[i][j] = __builtin_amdgcn_mfma_f32_16x16x32_bf16(af[i], bfr[j], acc[i][j], 0, 0, 0);
    __syncthreads();
  }

  long cbase = (long)z * sC;
  int mw = d.mw[y], out0 = d.out0[y];
#pragma unroll
  for (int i = 0; i < WM; ++i)
#pragma unroll
    for (int j = 0; j < WN; ++j)
#pragma unroll
      for (int r = 0; r < 4; ++r) {
        int loc = wm + i * 16 + q * 4 + r;
        int cg = n0 + wn + j * 16 + l15;
        if (loc < mw) {
          long idx = cbase + (long)(out0 + loc) * 960 + cg;
          Cp[idx] = f2bf(acc[i][j][r]);
        }
      }
}

// ---------- instance-norm + softmax over KV=960, in-place fp16 -> bf16 ----------
// Vectorized (G13): ushort4 loads/stores, 240 active lanes of 256.
__global__ __launch_bounds__(256)
void norm_softmax_all(_Float16* __restrict__ S, const float* __restrict__ stats) {
  long row = blockIdx.x;            // z*960 + cc
  int z = (int)(row / 960), cc = (int)(row % 960);
  int br = (cc < 64) ? 0 : (cc < 192) ? 1 : (cc < 448) ? 2 : 3;
  int Cbr = (br == 0) ? 64 : (br == 1) ? 128 : (br == 2) ? 256 : 512;
  float invCnt = 1.0f / ((float)Cbr * 960.0f);
  float m1 = stats[z * 8 + br * 2 + 0] * invCnt;
  float m2 = stats[z * 8 + br * 2 + 1] * invCnt;
  float rsig = rsqrtf(m2 - m1 * m1 + 1e-5f);
  unsigned short* s = (unsigned short*)(S + row * 960);
  int t = threadIdx.x;
  float e[4] = {0.f, 0.f, 0.f, 0.f};
  float acc = 0.f;
  if (t < 240) {
    ushort4 v = *reinterpret_cast<const ushort4*>(s + t * 4);
    union { unsigned short u; _Float16 h; } cv;
#pragma unroll
    for (int j = 0; j < 4; ++j) {
      cv.u = (&v.x)[j];
      e[j] = __expf(((float)cv.h - m1) * rsig);
      acc += e[j];
    }
  }
#pragma unroll
  for (int o = 32; o; o >>= 1) acc += __shfl_down(acc, o, 64);
  __shared__ float red[4];
  if ((t & 63) == 0) red[t >> 6] = acc;
  __syncthreads();
  float inv = 1.0f / (red[0] + red[1] + red[2] + red[3]);
  if (t < 240) {
    ushort4 o;
    o.x = f2bf(e[0] * inv); o.y = f2bf(e[1] * inv);
    o.z = f2bf(e[2] * inv); o.w = f2bf(e[3] * inv);
    *reinterpret_cast<ushort4*>(s + t * 4) = o;
  }
}

// ---------- 4-branch batched NT GEMM (out-proj), branch from bx ----------
struct MDesc {
  long aOff[4], bOff[4], cOff[4];
  long sAz[4], sBz[4], sCz[4];
  long iA[4], iB[4];
  int  lda[4], ldb[4], ldcv[4];
  int  Kk[4], Ncl[4], nIn[4];
  int  nstart[4];
  float alpha[4];
};

template<int OUT_F32>
__global__ __launch_bounds__(256)
void gemm_multi(const unsigned short* __restrict__ A0,
                const unsigned short* __restrict__ B0,
                void* __restrict__ Cp, MDesc d) {
  __shared__ unsigned short As[2][128 * 32];
  __shared__ unsigned short Bs[2][128 * 32];
  unsigned bxu, byu, bzu;
  xcd_swizzle(bxu, byu, bzu);
  int bx = (int)bxu;
  int br = (bx >= d.nstart[3]) ? 3 : (bx >= d.nstart[2]) ? 2 : (bx >= d.nstart[1]) ? 1 : 0;
  int z = (int)bzu;
  int n0 = (bx - d.nstart[br]) * 128;
  int m0 = (int)byu * 128;
  int K = d.Kk[br], lda = d.lda[br], ldb = d.ldb[br], ldc = d.ldcv[br];
  int Ncl = d.Ncl[br], nInner = d.nIn[br];
  long iA = d.iA[br], iB = d.iB[br];
  float alpha = d.alpha[br];
  const unsigned short* Ab = A0 + d.aOff[br] + (long)z * d.sAz[br];
  const unsigned short* Bb = B0 + d.bOff[br] + (long)z * d.sBz[br];

  int t = threadIdx.x, lane = t & 63, wave = t >> 6;
  int wm = (wave >> 1) * 64, wn = (wave & 1) * 64;
  int l15 = lane & 15, q = lane >> 4;
  int arow = t >> 2;
  int acol = ((t & 3) ^ ((t >> 3) & 3)) * 8;
  int rA0 = m0 + arow, rA1 = m0 + 64 + arow;
  int rB0 = min(n0 + arow, Ncl - 1), rB1 = min(n0 + 64 + arow, Ncl - 1);

  const unsigned short* Asrc = Ab;
  const unsigned short* Bsrc = Bb;
  int kk = 0;
  auto stage = [&](int bufSel) {
    __builtin_amdgcn_global_load_lds(
        (const __attribute__((address_space(1))) void*)(Asrc + (long)rA0 * lda + acol + kk),
        (__attribute__((address_space(3))) void*)(&As[bufSel][t * 8]), 16, 0, 0);
    __builtin_amdgcn_global_load_lds(
        (const __attribute__((address_space(1))) void*)(Asrc + (long)rA1 * lda + acol + kk),
        (__attribute__((address_space(3))) void*)(&As[bufSel][2048 + t * 8]), 16, 0, 0);
    __builtin_amdgcn_global_load_lds(
        (const __attribute__((address_space(1))) void*)(Bsrc + (long)rB0 * ldb + acol + kk),
        (__attribute__((address_space(3))) void*)(&Bs[bufSel][t * 8]), 16, 0, 0);
    __builtin_amdgcn_global_load_lds(
        (const __attribute__((address_space(1))) void*)(Bsrc + (long)rB1 * ldb + acol + kk),
        (__attribute__((address_space(3))) void*)(&Bs[bufSel][2048 + t * 8]), 16, 0, 0);
  };
  auto advance = [&]() { kk += 32; if (kk >= K) { kk = 0; Asrc += iA; Bsrc += iB; } };

  int nt = nInner * (K >> 5);
  f32x4 acc[4][4] = {};
  stage(0);
  advance();
  __syncthreads();
  for (int s = 0; s < nt; ++s) {
    int cur = s & 1;
    if (s + 1 < nt) { stage(cur ^ 1); advance(); }
    short8 af[4], bfr[4];
#pragma unroll
    for (int i = 0; i < 4; ++i) {
      int row = wm + i * 16 + l15;
      af[i] = *reinterpret_cast<const short8*>(&As[cur][row * 32 + swz_slot(row, q) * 8]);
    }
#pragma unroll
    for (int j = 0; j < 4; ++j) {
      int row = wn + j * 16 + l15;
      bfr[j] = *reinterpret_cast<const short8*>(&Bs[cur][row * 32 + swz_slot(row, q) * 8]);
    }
#pragma unroll
    for (int i = 0; i < 4; ++i)
#pragma unroll
      for (int j = 0; j < 4; ++j)
        acc[i][j] = __builtin_amdgcn_mfma_f32_16x16x32_bf16(af[i], bfr[j], acc[i][j], 0, 0, 0);
    __syncthreads();
  }

  long cb = d.cOff[br] + (long)z * d.sCz[br];
#pragma unroll
  for (int i = 0; i < 4; ++i)
#pragma unroll
    for (int j = 0; j < 4; ++j)
#pragma unroll
      for (int r = 0; r < 4; ++r) {
        float v = acc[i][j][r] * alpha;
        int rg = m0 + wm + i * 16 + q * 4 + r;
        int cg = n0 + wn + j * 16 + l15;
        if (cg < Ncl) {
          long idx = cb + (long)rg * ldc + cg;
          if (OUT_F32) ((float*)Cp)[idx] = v;
          else ((unsigned short*)Cp)[idx] = f2bf(v);
        }
      }
}

// ---------- host ----------
extern "C" void kernel_launch(void* const* d_in, const int* in_sizes, int n_in,
                              void* d_out, int out_size, void* d_ws, size_t ws_size,
                              hipStream_t stream) {
  const float* embs[4] = {(const float*)d_in[0], (const float*)d_in[1],
                          (const float*)d_in[2], (const float*)d_in[3]};
  const float* embA = (const float*)d_in[4];
  const float* Wk   = (const float*)d_in[9];
  const float* Wv   = (const float*)d_in[10];
  float* out = (float*)d_out;

  char* base = (char*)d_ws;
  size_t off = 0;
  auto take = [&](size_t bytes) -> void* {
    void* p = base + off;
    off += (bytes + 255) & ~(size_t)255;
    return p;
  };
  // contiguous cast destination region: EA | WQb | WKb | WOb (all 256B-multiples)
  unsigned short* EA    = (unsigned short*)take(15728640);  // embA bf16 [8][1024][960]
  unsigned short* WQb   = (unsigned short*)take(2785280);   // Wq1..4 bf16
  unsigned short* WKb   = (unsigned short*)take(7372800);   // Wk bf16 [4][960][960]
  unsigned short* WOb   = (unsigned short*)take(696320);    // Wo1..4 bf16
  unsigned short* embAT = (unsigned short*)take(15728640);  // embA^T [8][960][1024]; CT aliases
  unsigned short* embTc = (unsigned short*)take(15728640);  // concat emb^T [8][960][1024]
  unsigned short* WvT   = (unsigned short*)take(7372800);   // Wv^T [4][960][960]
  float*          ST    = (float*)take(1024);               // stats [32][4][2] f32
  unsigned short* GT    = (unsigned short*)take(14745600);  // G [8][960][960]; SPW aliases
  unsigned short* Tbuf  = (unsigned short*)take(58982400);  // T [32][960][960]
  char*           SCr   = (char*)take(58982400);            // scores fp16 -> probs bf16 in place
  _Float16*       SC    = (_Float16*)SCr;
  unsigned short* PR    = (unsigned short*)SCr;             // probs bf16 [32][960][960]
  unsigned short* SPW   = GT;                               // [8][960][960]  (G dead after T)
  unsigned short* CT    = embAT;                            // [8][1024][960] (embAT dead after G)

  if (ws_size < off) return;  // fail clean instead of faulting

  hipMemsetAsync(ST, 0, 1024, stream);

  const long Cs[4]     = {64, 128, 256, 512};
  const long c0s[4]    = {0, 64, 192, 448};
  const long woOff[4]  = {0, 4096, 20480, 86016};
  const long outOff[4] = {0, 524288, 1572864, 3670016};
  const float kscale = 0.0322748612f;  // 1/sqrt(960)
  YDesc ydDummy = {};

  // one fused cast for all plain fp32->bf16 segments (dst = EA..WOb contiguous)
  {
    CastDesc cd;
    const float* ss[10] = {embA, (const float*)d_in[5], (const float*)d_in[6],
                           (const float*)d_in[7], (const float*)d_in[8], Wk,
                           (const float*)d_in[11], (const float*)d_in[12],
                           (const float*)d_in[13], (const float*)d_in[14]};
    const long ln[10] = {7864320, 16384, 65536, 262144, 1048576, 3686400,
                         4096, 16384, 65536, 262144};
    long c = 0;
    for (int i = 0; i < 10; ++i) { cd.s[i] = ss[i]; cd.cum[i] = c; c += ln[i]; }
    cd.cum[10] = c;
    castN_kernel<<<4096, 256, 0, stream>>>(cd, EA, c >> 2);
  }
  // transpose-casts (3 launches)
  tcast_kernel<<<dim3(15, 16, 8), 256, 0, stream>>>(embA, embAT, 1024, 960, 983040, 983040);
  {
    T4Desc td; for (int i = 0; i < 4; ++i) td.src[i] = embs[i];
    tcast4_kernel<<<dim3(15, 16, 8), 256, 0, stream>>>(td, embTc);
  }
  tcast_kernel<<<dim3(15, 15, 4), 256, 0, stream>>>(Wv, WvT, 960, 960, 921600, 921600);

  // G[b][k][c] = sum_n embA[n,k]*emb_cat[n,c] : M=960, N=960, K=1024, z=8 (512 blocks)
  gemm_nt<128, 128, 0, 0, 0, 1><<<dim3(8, 8, 8), 256, 0, stream>>>(
      embAT, embTc, GT, 1024, 1024, 1024, 960, 1,
      983040L, 0L, 983040L, 0L, 921600L,
      1, 0L, 0L, 1.0f, nullptr, 960, 960, 960, 960, 0, ydDummy);

  // T[b,h][cc][k] = Wq_br[h] @ G[b] (block-diagonal over branch rows), one launch
  {
    BDesc d;
    const int brOf[8]  = {0, 1, 2, 2, 3, 3, 3, 3};
    const int ar0[8]   = {0, 0, 0, 128, 0, 128, 256, 384};
    const long wqOff[4] = {0, 16384, 81920, 344064};
    for (int y = 0; y < 8; ++y) {
      int br = brOf[y];
      int Ci = (int)Cs[br];
      d.K[y] = Ci;
      d.aRow0[y] = ar0[y];
      d.out0[y] = (int)c0s[br] + ar0[y];
      d.mw[y] = (br == 0) ? 64 : 128;
      d.bc[y] = (int)c0s[br];
      d.aOff[y] = wqOff[br];
      d.aH[y] = (long)Ci * Ci;
    }
    gemm_bd<<<dim3(15, 8, 32), 256, 0, stream>>>(WQb, GT, Tbuf, 960, 921600L, 921600L, d);
  }

  // scores[b,h][cc][o] = kscale * T[b,h] @ Wk[h]^T, fp16 out + per-branch stats (2048 blocks)
  // SWZ=0: r7 config (105us) — swizzle neutral/negative on this launch (r8).
  {
    YDesc yd;
    const int m0s[8] = {0, 64, 192, 320, 448, 576, 704, 832};
    const int mws[8] = {64, 128, 128, 128, 128, 128, 128, 128};
    const int brs[8] = {0, 1, 2, 2, 3, 3, 3, 3};
    for (int y = 0; y < 8; ++y) { yd.m0[y] = m0s[y]; yd.mw[y] = mws[y]; yd.br[y] = brs[y]; }
    gemm_nt<128, 128, 2, 1, 1, 0><<<dim3(8, 8, 32), 256, 0, stream>>>(
        Tbuf, WKb, SC, 960, 960, 960, 960, 4,
        3686400L, 921600L, 0L, 921600L, 921600L,
        1, 0L, 0L, kscale, ST, 960, 960, 960, 960, 960, yd);
  }

  // instance-norm + softmax, in place (fp16 scores -> bf16 probs), one launch
  norm_softmax_all<<<dim3(32 * 960), 256, 0, stream>>>(SC, ST);

  // SPW[b][cc][k] = 0.25 * sum_h probs[b,h] @ WvT[h] : z=8, nInner=4 (512 blocks)
  gemm_nt<128, 128, 0, 0, 0, 1><<<dim3(8, 8, 8), 256, 0, stream>>>(
      PR, WvT, SPW, 960, 960, 960, 960, 1,
      3686400L, 0L, 0L, 0L, 921600L,
      4, 921600L, 921600L, 0.25f, nullptr, 960, 960, 960, 960, 0, ydDummy);

  // CT[b][n][cc] = embA[b] @ SPW[b]^T : M=1024, N=960, K=960, z=8 (512 blocks)
  gemm_nt<128, 128, 0, 0, 0, 1><<<dim3(8, 8, 8), 256, 0, stream>>>(
      EA, SPW, CT, 960, 960, 960, 960, 1,
      983040L, 0L, 921600L, 0L, 983040L,
      1, 0L, 0L, 1.0f, nullptr, 1024, 960, 1024, 960, 0, ydDummy);

  // out-all: out[b,n,c'] = CT[b][:, branch cols] @ Wo^T, one launch (512 blocks)
  {
    MDesc d;
    for (int i = 0; i < 4; ++i) {
      long C = Cs[i];
      d.aOff[i] = c0s[i];       d.sAz[i] = 983040L;          d.iA[i] = 0;
      d.bOff[i] = woOff[i];     d.sBz[i] = 0;                d.iB[i] = 0;
      d.cOff[i] = outOff[i];    d.sCz[i] = 1024L * C;
      d.lda[i] = 960; d.ldb[i] = (int)C; d.ldcv[i] = (int)C;
      d.Kk[i] = (int)C; d.Ncl[i] = (int)C; d.nIn[i] = 1;
      d.alpha[i] = 1.0f;
    }
    d.nstart[0] = 0; d.nstart[1] = 1; d.nstart[2] = 2; d.nstart[3] = 4;
    gemm_multi<1><<<dim3(8, 8, 8), 256, 0, stream>>>(CT, WOb, out, d);
  }
  (void)in_sizes; (void)n_in; (void)out_size;
}